// Round 1
// baseline (789.871 us; speedup 1.0000x reference)
//
#include <hip/hip_runtime.h>
#include <hip/hip_bf16.h>
#include <math.h>

#define BB 16
#define SS 768
#define DE 16
#define HID 128

// ws (float) layout:
//  [0]            : pocket-mask layout flag (int; 1 = byte layout, 0 = 32-bit layout)
//  [16..144)      : v_node[128]  = W_node @ W_imp[0:32]
//  [144..208)     : u_e[64]      = W_e2  @ W_imp[32:64]
//  [208]          : cterm        = b_node.W_imp[0:32] + b_e2.W_imp[32:64] + b_imp
//  [256..12544)   : imp[B*S]
//  [12544..24832) : dist[B*S]

__global__ __launch_bounds__(256) void sniff_kernel(const unsigned int* __restrict__ pm,
                                                    int* __restrict__ flag) {
    __shared__ int bad;
    int tid = threadIdx.x;
    if (tid == 0) bad = 0;
    __syncthreads();
    // First (B*S)/4 words are within the buffer under every candidate layout.
    for (int t = tid; t < (BB * SS) / 4; t += 256) {
        unsigned int w = pm[t];
        if (w > 1u && w != 0x3F800000u) bad = 1;  // impossible for int32 0/1 or f32 0.0/1.0
    }
    __syncthreads();
    if (tid == 0) *flag = bad;
}

__global__ __launch_bounds__(128) void precompute_kernel(
    const float* __restrict__ Wn, const float* __restrict__ bn,
    const float* __restrict__ We2, const float* __restrict__ be2,
    const float* __restrict__ Wimp, const float* __restrict__ bimp,
    float* __restrict__ ws) {
    int tid = threadIdx.x;
    if (tid < 128) {
        float s = 0.f;
        for (int c = 0; c < 32; ++c) s += Wn[tid * 32 + c] * Wimp[c];
        ws[16 + tid] = s;
    }
    if (tid < 64) {
        float s = 0.f;
        for (int c = 0; c < 32; ++c) s += We2[tid * 32 + c] * Wimp[32 + c];
        ws[144 + tid] = s;
    }
    if (tid == 0) {
        float s = bimp[0];
        for (int c = 0; c < 32; ++c) s += bn[c] * Wimp[c];
        for (int c = 0; c < 32; ++c) s += be2[c] * Wimp[32 + c];
        ws[208] = s;
    }
}

__global__ __launch_bounds__(256) void edge_kernel(
    const float4* __restrict__ edge, const float* __restrict__ nf,
    const void* __restrict__ pmask, const float* __restrict__ seqmask,
    const float* __restrict__ We1, const float* __restrict__ be1,
    float* __restrict__ ws) {
    const int tid = threadIdx.x;
    const int bi = blockIdx.x;          // b*S + i
    const int b = bi / SS;

    __shared__ float s_a[256];
    __shared__ float s_b[256];
    __shared__ unsigned char s_m[SS];

    const int flag = ((const int*)ws)[0];
    if (flag) {
        const unsigned char* pm = (const unsigned char*)pmask + (size_t)b * SS;
        for (int j = tid; j < SS; j += 256) s_m[j] = pm[j] ? 1 : 0;
    } else {
        const unsigned int* pm = (const unsigned int*)pmask + (size_t)b * SS;
        for (int j = tid; j < SS; j += 256) s_m[j] = pm[j] ? 1 : 0;
    }
    __syncthreads();

    const float4* row = edge + (size_t)bi * (SS * DE / 4);  // 3072 float4 per row
    float sum = 0.f;
    float dmin = INFINITY;
#pragma unroll
    for (int it = 0; it < 12; ++it) {
        int t = tid + it * 256;
        float4 v = row[t];
        sum += (v.x + v.y) + (v.z + v.w);
        if ((t & 3) == 0) {                 // v.x is channel 0 of column j = t>>2
            if (s_m[t >> 2]) dmin = fminf(dmin, v.x);
        }
    }
    s_a[tid] = sum;
    s_b[tid] = dmin;
    __syncthreads();
    for (int off = 128; off > 0; off >>= 1) {
        if (tid < off) {
            s_a[tid] += s_a[tid + off];
            s_b[tid] = fminf(s_b[tid], s_b[tid + off]);
        }
        __syncthreads();
    }
    const float total = s_a[0];
    const float dall = s_b[0];
    __syncthreads();

    const float es = total * (1.0f / (float)(SS * DE));
    float p = 0.f;
    if (tid < 128) p += nf[(size_t)bi * HID + tid] * ws[16 + tid];
    if (tid < 64) {
        float h = es * We1[tid] + be1[tid];
        h = fmaxf(h, 0.f);
        p += h * ws[144 + tid];
    }
    s_a[tid] = p;
    __syncthreads();
    for (int off = 128; off > 0; off >>= 1) {
        if (tid < off) s_a[tid] += s_a[tid + off];
        __syncthreads();
    }
    if (tid == 0) {
        float logit = s_a[0] + ws[208];
        float impv = seqmask[bi] / (1.f + expf(-logit));
        ws[256 + bi] = impv;
        ws[256 + BB * SS + bi] = dall;
    }
}

__global__ __launch_bounds__(256) void final_kernel(
    const void* __restrict__ pmask, const float* __restrict__ ws,
    float* __restrict__ out) {
    const int tid = threadIdx.x;
    const int b = blockIdx.x;
    __shared__ float s_f[256];
    __shared__ int s_i[256];

    const float* imp = ws + 256;
    const float* dist = ws + 256 + BB * SS;
    const int flag = ((const int*)ws)[0];

    float psum = 0.f;
    int por = 0;
    for (int i = tid; i < SS; i += 256) {
        psum += imp[b * SS + i];
        int m = flag ? (((const unsigned char*)pmask)[b * SS + i] != 0)
                     : (((const unsigned int*)pmask)[b * SS + i] != 0u);
        por |= m;
    }
    s_f[tid] = psum;
    s_i[tid] = por;
    __syncthreads();
    for (int off = 128; off > 0; off >>= 1) {
        if (tid < off) {
            s_f[tid] += s_f[tid + off];
            s_i[tid] |= s_i[tid + off];
        }
        __syncthreads();
    }
    const float imp_mean = s_f[0] / (float)SS;
    const int haspocket = s_i[0];
    __syncthreads();

    int cnt = 0;
    for (int i = tid; i < SS; i += 256) {
        int m = flag ? (((const unsigned char*)pmask)[b * SS + i] != 0)
                     : (((const unsigned int*)pmask)[b * SS + i] != 0u);
        float d = dist[b * SS + i];
        bool core = d < 6.0f;
        bool shell = (d >= 6.0f) && (d < 10.0f) && (imp[b * SS + i] > imp_mean);
        cnt += (m || core || shell) ? 1 : 0;
    }
    s_i[tid] = cnt;
    __syncthreads();
    for (int off = 128; off > 0; off >>= 1) {
        if (tid < off) s_i[tid] += s_i[tid + off];
        __syncthreads();
    }
    if (tid == 0) {
        float chunk;
        if (haspocket) {
            float ml = fminf((float)s_i[0], 256.f);   // merged_len clamp
            chunk = fminf(fmaxf(ml, 64.f), 256.f);    // adj=64, MAX_SEQ_LEN=256
        } else {
            chunk = fminf(fmaxf(64.f * imp_mean, 32.f), 128.f);
        }
        out[b] = chunk;
        if (b == 0) out[BB] = 256.f;                  // MAX_SEQ_LEN output
    }
}

extern "C" void kernel_launch(void* const* d_in, const int* in_sizes, int n_in,
                              void* d_out, int out_size, void* d_ws, size_t ws_size,
                              hipStream_t stream) {
    const float* nf = (const float*)d_in[0];
    const float4* edge = (const float4*)d_in[1];
    const float* seqmask = (const float*)d_in[2];
    const void* pmask = d_in[3];
    const float* Wn = (const float*)d_in[4];
    const float* bn = (const float*)d_in[5];
    const float* We1 = (const float*)d_in[6];
    const float* be1 = (const float*)d_in[7];
    const float* We2 = (const float*)d_in[8];
    const float* be2 = (const float*)d_in[9];
    const float* Wimp = (const float*)d_in[10];
    const float* bimp = (const float*)d_in[11];
    float* ws = (float*)d_ws;
    float* out = (float*)d_out;

    sniff_kernel<<<1, 256, 0, stream>>>((const unsigned int*)pmask, (int*)ws);
    precompute_kernel<<<1, 128, 0, stream>>>(Wn, bn, We2, be2, Wimp, bimp, ws);
    edge_kernel<<<BB * SS, 256, 0, stream>>>(edge, nf, pmask, seqmask, We1, be1, ws);
    final_kernel<<<BB, 256, 0, stream>>>(pmask, ws, out);
}